// Round 25
// baseline (192.818 us; speedup 1.0000x reference)
//
#include <hip/hip_runtime.h>
#include <math.h>

// Problem constants (LocallyEnhancedAttention: B=16, N=3136, C=256, SR=7, HEADS=8)
#define B_     16
#define H_IMG  56
#define W_IMG  56
#define N_TOK  3136      // 56*56
#define C_     256
#define C4_    64        // C_/4
#define NHEAD  8
#define HDIM   32
#define NCH    8         // attn chunks (each = 7 image rows)

typedef float f32x4 __attribute__((ext_vector_type(4)));
typedef __bf16 bf16x8 __attribute__((ext_vector_type(8)));

// gelu(x) = 0.5 x (1 + erf(x/sqrt(2))) with branchless poly erf
// (Abramowitz-Stegun 7.1.26, |err| <= 1.5e-7).
__device__ __forceinline__ float geluf(float x) {
    float a = fabsf(x) * 0.70710678118654752f;
    float t = 1.0f / fmaf(0.3275911f, a, 1.0f);
    float poly = t * fmaf(t, fmaf(t, fmaf(t, fmaf(t, 1.061405429f, -1.453152027f),
                        1.421413741f), -0.284496736f), 0.254829592f);
    float erfa = fmaf(-poly, __expf(-a * a), 1.0f);
    float erfs = copysignf(erfa, x);
    return 0.5f * x * (1.0f + erfs);
}

// 8 -> 56 bilinear (half-pixel + edge renormalize == index clamp). f = (o-3)/7
__device__ __forceinline__ void up_coef(int o, int& i0, int& i1, float& t) {
    float f  = (float)(o - 3) * (1.0f / 7.0f);
    float fl = floorf(f);
    int   ii = (int)fl;
    t = f - fl;
    if (ii < 0)       { i0 = 0; i1 = 0; t = 0.0f; }
    else if (ii >= 7) { i0 = 7; i1 = 7; t = 0.0f; }
    else              { i0 = ii; i1 = ii + 1; }
}

__device__ __forceinline__ void split_bf16(float4 f, uint2& hi, uint2& lo) {
    unsigned u0 = __float_as_uint(f.x), u1 = __float_as_uint(f.y);
    unsigned u2 = __float_as_uint(f.z), u3 = __float_as_uint(f.w);
    unsigned h0 = u0 & 0xFFFF0000u, h1 = u1 & 0xFFFF0000u;
    unsigned h2 = u2 & 0xFFFF0000u, h3 = u3 & 0xFFFF0000u;
    hi = make_uint2((h0 >> 16) | h1, (h2 >> 16) | h3);
    float l0 = f.x - __uint_as_float(h0);
    float l1 = f.y - __uint_as_float(h1);
    float l2 = f.z - __uint_as_float(h2);
    float l3 = f.w - __uint_as_float(h3);
    lo = make_uint2((__float_as_uint(l0) >> 16) | (__float_as_uint(l1) & 0xFFFF0000u),
                    (__float_as_uint(l2) >> 16) | (__float_as_uint(l3) & 0xFFFF0000u));
}

__device__ __forceinline__ unsigned pack2_bf16(float a, float b) {
    __bf16 ha = (__bf16)a, hb = (__bf16)b;
    unsigned short ua = __builtin_bit_cast(unsigned short, ha);
    unsigned short ub = __builtin_bit_cast(unsigned short, hb);
    return (unsigned)ua | ((unsigned)ub << 16);
}

// Async global->LDS, 16B per lane (wave-uniform LDS base + lane*16).
__device__ __forceinline__ void gload_lds16(const float* g, float* l) {
    __builtin_amdgcn_global_load_lds(
        (const __attribute__((address_space(1))) unsigned int*)g,
        (__attribute__((address_space(3))) unsigned int*)l, 16, 0, 0);
}

// ---------------------------------------------------------------------------
// Prep (PARALLEL): blocks 0-8 transpose tap t of all 3 weight sets; block 9
// folds BN into scale/shift.
// ---------------------------------------------------------------------------
__global__ void prep_kernel(
    const float* __restrict__ w1, const float* __restrict__ w2, const float* __restrict__ w3,
    const float* __restrict__ g1, const float* __restrict__ b1, const float* __restrict__ m1, const float* __restrict__ v1,
    const float* __restrict__ g2, const float* __restrict__ b2, const float* __restrict__ m2, const float* __restrict__ v2,
    const float* __restrict__ g3, const float* __restrict__ b3, const float* __restrict__ m3, const float* __restrict__ v3,
    float* __restrict__ wT1, float* __restrict__ wT2, float* __restrict__ wT3,
    float* __restrict__ sc1, float* __restrict__ sh1,
    float* __restrict__ sc2, float* __restrict__ sh2,
    float* __restrict__ sc3, float* __restrict__ sh3)
{
    int c = threadIdx.x;
    int blk = blockIdx.x;
    if (blk < 9) {
        wT1[blk * C_ + c] = w1[c * 9 + blk];
        wT2[blk * C_ + c] = w2[c * 9 + blk];
        wT3[blk * C_ + c] = w3[c * 9 + blk];
    } else {
        float s1 = g1[c] * rsqrtf(v1[c] + 1e-5f); sc1[c] = s1; sh1[c] = b1[c] - m1[c] * s1;
        float s2 = g2[c] * rsqrtf(v2[c] + 1e-5f); sc2[c] = s2; sh2[c] = b2[c] - m2[c] * s2;
        float s3 = g3[c] * rsqrtf(v3[c] + 1e-5f); sc3[c] = s3; sh3[c] = b3[c] - m3[c] * s3;
    }
}

// ---------------------------------------------------------------------------
// MFMA GEMM (NT) — m97 staging + T1 swizzle, 3 blocks/CU (verified).
// ---------------------------------------------------------------------------
__global__ __launch_bounds__(256, 3) void gemm_nt_mfma_kernel(
    const float* __restrict__ A, const float* __restrict__ Bm,
    const float* __restrict__ bias, float* __restrict__ C, int M, int N)
{
    __shared__ float lds[8192];
    const int tid  = threadIdx.x;
    const int nb   = N >> 7;
    const int nwg  = (M >> 7) * nb;
    const int cpx  = nwg >> 3;
    const int bid  = blockIdx.x;
    const int swz  = (bid & 7) * cpx + (bid >> 3);
    const int bx   = swz % nb;
    const int by   = swz / nb;
    const int lane = tid & 63;
    const int wv   = tid >> 6;
    const int wr   = wv >> 1, wc = wv & 1;
    const int l15  = lane & 15, kb = lane >> 4;

    const float* Abase = A  + (size_t)(by * 128) * 256;
    const float* Bbase = Bm + (size_t)(bx * 128) * 256;

    f32x4 acc[4][4];
#pragma unroll
    for (int m = 0; m < 4; ++m)
#pragma unroll
        for (int n = 0; n < 4; ++n) acc[m][n] = (f32x4)(0.0f);

    int srow[4], ssk[4];
#pragma unroll
    for (int i = 0; i < 4; ++i) {
        int u = i * 256 + tid;
        srow[i] = u >> 3;
        ssk[i]  = ((u & 7) ^ (srow[i] & 7)) << 2;
    }

#pragma unroll
    for (int k0 = 0; k0 < 256; k0 += 32) {
        __syncthreads();
#pragma unroll
        for (int i = 0; i < 4; ++i) {
            int u = i * 256 + tid;
            gload_lds16(Abase + (size_t)srow[i] * 256 + k0 + ssk[i], &lds[u * 4]);
        }
#pragma unroll
        for (int i = 0; i < 4; ++i) {
            int u = i * 256 + tid;
            gload_lds16(Bbase + (size_t)srow[i] * 256 + k0 + ssk[i], &lds[4096 + u * 4]);
        }
        __syncthreads();

        bf16x8 ah[4], al[4], bh[4], bl[4];
#pragma unroll
        for (int m = 0; m < 4; ++m) {
            int r = wr * 64 + m * 16 + l15;
            float4 f0 = *(const float4*)&lds[r * 32 + ((((kb * 2)    ) ^ (r & 7)) << 2)];
            float4 f1 = *(const float4*)&lds[r * 32 + ((((kb * 2) + 1) ^ (r & 7)) << 2)];
            uint2 h0, l0, h1, l1;
            split_bf16(f0, h0, l0);
            split_bf16(f1, h1, l1);
            ah[m] = __builtin_bit_cast(bf16x8, make_uint4(h0.x, h0.y, h1.x, h1.y));
            al[m] = __builtin_bit_cast(bf16x8, make_uint4(l0.x, l0.y, l1.x, l1.y));
        }
#pragma unroll
        for (int n = 0; n < 4; ++n) {
            int r = wc * 64 + n * 16 + l15;
            float4 f0 = *(const float4*)&lds[4096 + r * 32 + ((((kb * 2)    ) ^ (r & 7)) << 2)];
            float4 f1 = *(const float4*)&lds[4096 + r * 32 + ((((kb * 2) + 1) ^ (r & 7)) << 2)];
            uint2 h0, l0, h1, l1;
            split_bf16(f0, h0, l0);
            split_bf16(f1, h1, l1);
            bh[n] = __builtin_bit_cast(bf16x8, make_uint4(h0.x, h0.y, h1.x, h1.y));
            bl[n] = __builtin_bit_cast(bf16x8, make_uint4(l0.x, l0.y, l1.x, l1.y));
        }
#pragma unroll
        for (int m = 0; m < 4; ++m)
#pragma unroll
            for (int n = 0; n < 4; ++n) {
                acc[m][n] = __builtin_amdgcn_mfma_f32_16x16x32_bf16(ah[m], bh[n], acc[m][n], 0, 0, 0);
                acc[m][n] = __builtin_amdgcn_mfma_f32_16x16x32_bf16(ah[m], bl[n], acc[m][n], 0, 0, 0);
                acc[m][n] = __builtin_amdgcn_mfma_f32_16x16x32_bf16(al[m], bh[n], acc[m][n], 0, 0, 0);
            }
    }

    const int rb = by * 128 + wr * 64 + kb * 4;
    const int cb = bx * 128 + wc * 64 + l15;
#pragma unroll
    for (int n = 0; n < 4; ++n) {
        int col = cb + n * 16;
        float bv = bias ? bias[col] : 0.0f;
#pragma unroll
        for (int m = 0; m < 4; ++m) {
            int row = rb + m * 16;
#pragma unroll
            for (int r = 0; r < 4; ++r)
                C[(size_t)(row + r) * N + col] = acc[m][n][r] + bv;
        }
    }
}

// ---------------------------------------------------------------------------
// FUSED conv1+conv2, quarter-channel split, LDS-staged input tile (R24 win)
// + XOR bank swizzle instead of row pad, ps aliased into dead tile rows:
// LDS = exactly 32768 B -> 5 blocks/CU (was 37.4KB / 4 blocks).
// Tile index: TIX(row,q) = row*16 + (q ^ (row&7)) — same formula on write
// and read, bijective per row, spreads bank groups across rows.
// ps (pool partials, 256 float4) lives at sg+1696 (tile rows >=106, only
// touched in A1/A2; barriers order the reuse).
// ---------------------------------------------------------------------------
#define TIX(row, q) (((row) << 4) + ((q) ^ ((row) & 7)))
__global__ __launch_bounds__(256, 5) void dwconv12_fused_kernel(
    const float* __restrict__ v,
    const float* __restrict__ wT1, const float* __restrict__ sc1v, const float* __restrict__ sh1v,
    const float* __restrict__ wT2, const float* __restrict__ sc2v, const float* __restrict__ sh2v,
    float* __restrict__ s2g, float* __restrict__ qpool, float* __restrict__ kpool)
{
    __shared__ float4 sg[2048];       // 32768 B exactly: tile + aliased ps
    float4* ps = sg + 1696;           // [16][16] flat, rows >=106 of tile

    const int blk = blockIdx.x;
    const int xcd = blk & 7;
    const int j   = blk >> 3;              // 0..511
    const int b   = xcd + 8 * (j >> 8);    // 2 images per XCD
    const int rem = j & 255;
    const int g   = rem >> 2;
    const int ch  = rem & 3;
    const int gy  = g >> 3, gx = g & 7;
    const int tid = threadIdx.x;
    const int q16 = tid & 15;
    const int slot = tid >> 4;             // 0..15
    const int c0  = ch * 64 + q16 * 4;

    const float4 sc1 = *(const float4*)(sc1v + c0);
    const float4 sh1 = *(const float4*)(sh1v + c0);

    float4 w1r[9];
#pragma unroll
    for (int t = 0; t < 9; ++t) w1r[t] = *(const float4*)(wT1 + t * C_ + c0);

    const int y0 = gy * 7, x0 = gx * 7;
    const float* inb = v + (size_t)b * N_TOK * C_ + ch * 64;

    // ---- A1: cooperative 11x11 input tile load (zeros outside image) ----
    for (int idx = tid; idx < 121 * 16; idx += 256) {
        int pin = idx >> 4, q = idx & 15;
        int ry  = pin / 11;
        int iy  = y0 - 2 + ry;
        int ix  = x0 - 2 + (pin - ry * 11);
        float4 val = make_float4(0.f, 0.f, 0.f, 0.f);
        if ((unsigned)iy < (unsigned)H_IMG && (unsigned)ix < (unsigned)W_IMG)
            val = *(const float4*)(inb + (size_t)(iy * W_IMG + ix) * C_ + q * 4);
        sg[TIX(pin, q)] = val;
    }
    __syncthreads();

    // ---- A2: conv1 + BN from LDS into registers (static indexing) ----
    float4 s1r[6];
    float4 qacc = make_float4(0.f, 0.f, 0.f, 0.f);
#pragma unroll
    for (int it = 0; it < 6; ++it) {
        const int p = slot + it * 16;
        if (p < 81) {
            const int py = p / 9, px = p - (p / 9) * 9;
            float cx = 0.f, cy = 0.f, cz = 0.f, cw = 0.f;
#pragma unroll
            for (int dy = 0; dy < 3; ++dy)
#pragma unroll
                for (int dx = 0; dx < 3; ++dx) {
                    const int row = (py + dy) * 11 + (px + dx);
                    const float4 iv = sg[TIX(row, q16)];
                    const float4 w  = w1r[dy * 3 + dx];
                    cx = fmaf(iv.x, w.x, cx);
                    cy = fmaf(iv.y, w.y, cy);
                    cz = fmaf(iv.z, w.z, cz);
                    cw = fmaf(iv.w, w.w, cw);
                }
            float4 s1;
            s1.x = cx * sc1.x + sh1.x;
            s1.y = cy * sc1.y + sh1.y;
            s1.z = cz * sc1.z + sh1.z;
            s1.w = cw * sc1.w + sh1.w;
            s1r[it] = s1;
            const float msk = (py >= 1 && py <= 7 && px >= 1 && px <= 7) ? 1.0f : 0.0f;
            qacc.x = fmaf(msk, s1.x, qacc.x);
            qacc.y = fmaf(msk, s1.y, qacc.y);
            qacc.z = fmaf(msk, s1.z, qacc.z);
            qacc.w = fmaf(msk, s1.w, qacc.w);
        } else {
            s1r[it] = make_float4(0.f, 0.f, 0.f, 0.f);
        }
    }
    __syncthreads();   // all tile reads done before overwrite (incl. ps alias)

    // ---- A3: write gelu(s1) into sg rows 0..80 (9-wide layout) ----
#pragma unroll
    for (int it = 0; it < 6; ++it) {
        const int p = slot + it * 16;
        if (p < 81) {
            const int py = p / 9, px = p - (p / 9) * 9;
            const int oy = y0 - 1 + py, ox = x0 - 1 + px;
            const bool pv = ((unsigned)oy < (unsigned)H_IMG) && ((unsigned)ox < (unsigned)W_IMG);
            const float4 s1 = s1r[it];
            float4 o;
            o.x = pv ? geluf(s1.x) : 0.0f;
            o.y = pv ? geluf(s1.y) : 0.0f;
            o.z = pv ? geluf(s1.z) : 0.0f;
            o.w = pv ? geluf(s1.w) : 0.0f;
            sg[TIX(p, q16)] = o;
        }
    }
    ps[slot * 16 + q16] = qacc;
    __syncthreads();

    // ---- q-pool reduce + write ----
    if (tid < 16) {
        float4 s = ps[tid];
#pragma unroll
        for (int t = 1; t < 16; ++t) {
            float4 u = ps[t * 16 + tid];
            s.x += u.x; s.y += u.y; s.z += u.z; s.w += u.w;
        }
        const float r = 1.0f / 49.0f;
        *(float4*)(qpool + ((size_t)b * 64 + g) * C_ + ch * 64 + tid * 4) =
            make_float4(s.x * r, s.y * r, s.z * r, s.w * r);
    }

    // ---- Phase C: conv2 from LDS ----
    float4 w2r[9];
#pragma unroll
    for (int t = 0; t < 9; ++t) w2r[t] = *(const float4*)(wT2 + t * C_ + c0);
    const float4 sc2 = *(const float4*)(sc2v + c0);
    const float4 sh2 = *(const float4*)(sh2v + c0);

    float4 kacc = make_float4(0.f, 0.f, 0.f, 0.f);
    for (int p2 = slot; p2 < 49; p2 += 16) {
        int qy = p2 / 7, qx = p2 - qy * 7;
        float cx = 0.f, cy = 0.f, cz = 0.f, cw = 0.f;
#pragma unroll
        for (int dy = 0; dy < 3; ++dy)
#pragma unroll
            for (int dx = 0; dx < 3; ++dx) {
                const int row = (qy + dy) * 9 + (qx + dx);
                const float4 t4 = sg[TIX(row, q16)];
                const float4 w  = w2r[dy * 3 + dx];
                cx = fmaf(t4.x, w.x, cx);
                cy = fmaf(t4.y, w.y, cy);
                cz = fmaf(t4.z, w.z, cz);
                cw = fmaf(t4.w, w.w, cw);
            }
        float s2x = cx * sc2.x + sh2.x;
        float s2y = cy * sc2.y + sh2.y;
        float s2z = cz * sc2.z + sh2.z;
        float s2w = cw * sc2.w + sh2.w;
        kacc.x += s2x; kacc.y += s2y; kacc.z += s2z; kacc.w += s2w;
        *(float4*)(s2g + ((size_t)b * N_TOK + (y0 + qy) * W_IMG + (x0 + qx)) * C_ + c0) =
            make_float4(geluf(s2x), geluf(s2y), geluf(s2z), geluf(s2w));
    }
    __syncthreads();   // ps reuse (C reads rows <=80 only, no overlap)
    ps[slot * 16 + q16] = kacc;
    __syncthreads();
    if (tid < 16) {
        float4 s = ps[tid];
#pragma unroll
        for (int t = 1; t < 16; ++t) {
            float4 u = ps[t * 16 + tid];
            s.x += u.x; s.y += u.y; s.z += u.z; s.w += u.w;
        }
        const float r = 1.0f / 49.0f;
        *(float4*)(kpool + ((size_t)b * 64 + g) * C_ + ch * 64 + tid * 4) =
            make_float4(s.x * r, s.y * r, s.z * r, s.w * r);
    }
}
#undef TIX

// ---------------------------------------------------------------------------
// FUSED conv3x3(bilinear_up(o_small)) + BN + add — hoisted (verified R13+).
// ---------------------------------------------------------------------------
__global__ __launch_bounds__(256, 3) void dwconv_up_bn_add_kernel(
    const float* __restrict__ osm, const float* __restrict__ wT,
    const float* __restrict__ scv, const float* __restrict__ shv,
    const float* __restrict__ add_, float* __restrict__ out)
{
    const int blk = blockIdx.x;
    const int xcd = blk & 7;
    const int j   = blk >> 3;
    const int b   = xcd + 8 * (j >> 6);
    const int g   = j & 63;
    const int gy  = g >> 3, gx = g & 7;
    const int tid = threadIdx.x;
    const int c4  = tid & 63;
    const int wv  = tid >> 6;
    const int c0  = c4 * 4;

    float4 wr[9];
#pragma unroll
    for (int t = 0; t < 9; ++t) wr[t] = *(const float4*)(wT + t * C_ + c0);
    const float4 sc = *(const float4*)(scv + c0);
    const float4 sh = *(const float4*)(shv + c0);

    const float* ob = osm + (size_t)b * 64 * C_ + c0;
    const int cry0 = max(gy - 1, 0), cry2 = min(gy + 1, 7);
    const int crx0 = max(gx - 1, 0), crx2 = min(gx + 1, 7);
    float4 P[3][3];
#pragma unroll
    for (int ri = 0; ri < 3; ++ri) {
        const int rowc = (ri == 0) ? cry0 : ((ri == 1) ? gy : cry2);
        P[ri][0] = *(const float4*)(ob + (size_t)(rowc * 8 + crx0) * C_);
        P[ri][1] = *(const float4*)(ob + (size_t)(rowc * 8 + gx)   * C_);
        P[ri][2] = *(const float4*)(ob + (size_t)(rowc * 8 + crx2) * C_);
    }

    for (int cpass = 0; cpass < 2; ++cpass) {
        const int xi = wv + cpass * 4;
        if (xi >= 7) break;
        const int x = gx * 7 + xi;

        float axw[3][3];
#pragma unroll
        for (int e = 0; e < 3; ++e) {
            int xx = x - 1 + e;
            if (xx >= 0 && xx < W_IMG) {
                int i0, i1; float t;
                up_coef(xx, i0, i1, t);
                const bool r0 = (i0 - gx + 1) == 0;
                axw[e][0] = r0 ? (1.0f - t) : 0.0f;
                axw[e][1] = r0 ? t : (1.0f - t);
                axw[e][2] = r0 ? 0.0f : t;
            } else {
                axw[e][0] = 0.0f; axw[e][1] = 0.0f; axw[e][2] = 0.0f;
            }
        }

        float4 S[3][3];
#pragma unroll
        for (int d = 0; d < 3; ++d) {
            float4 cw0, cw1, cw2;
#pragma unroll
            for (int ci = 0; ci < 3; ++ci) {
                float4 c;
                c.x = wr[d*3+0].x * axw[0][ci] + wr[d*3+1].x * axw[1][ci] + wr[d*3+2].x * axw[2][ci];
                c.y = wr[d*3+0].y * axw[0][ci] + wr[d*3+1].y * axw[1][ci] + wr[d*3+2].y * axw[2][ci];
                c.z = wr[d*3+0].z * axw[0][ci] + wr[d*3+1].z * axw[1][ci] + wr[d*3+2].z * axw[2][ci];
                c.w = wr[d*3+0].w * axw[0][ci] + wr[d*3+1].w * axw[1][ci] + wr[d*3+2].w * axw[2][ci];
                if (ci == 0) cw0 = c; else if (ci == 1) cw1 = c; else cw2 = c;
            }
#pragma unroll
            for (int ri = 0; ri < 3; ++ri) {
                float4 s;
                s.x = cw0.x * P[ri][0].x + cw1.x * P[ri][1].x + cw2.x * P[ri][2].x;
                s.y = cw0.y * P[ri][0].y + cw1.y * P[ri][1].y + cw2.y * P[ri][2].y;
                s.z = cw0.z * P[ri][0].z + cw1.z * P[ri][1].z + cw2.z * P[ri][2].z;
                s.w = cw0.w * P[ri][0].w + cw1.w * P[ri][1].w + cw2.w * P[ri][2].w;
                S[d][ri] = s;
            }
        }

#pragma unroll
        for (int y7 = 0; y7 < 7; ++y7) {
            const int y = gy * 7 + y7;
            float ax = 0.f, ay = 0.f, az = 0.f, aw = 0.f;
#pragma unroll
            for (int d = 0; d < 3; ++d) {
                const int yy = y + d - 1;
                if (yy < 0 || yy >= H_IMG) continue;
                int i0, i1; float ty;
                up_coef(yy, i0, i1, ty);
                const bool hi2 = (i0 - gy + 1) != 0;
                const float4 lo = hi2 ? S[d][1] : S[d][0];
                const float4 hi = hi2 ? S[d][2] : S[d][1];
                ax += fmaf(ty, hi.x - lo.x, lo.x);
                ay += fmaf(ty, hi.y - lo.y, lo.y);
                az += fmaf(ty, hi.z - lo.z, lo.z);
                aw += fmaf(ty, hi.w - lo.w, lo.w);
            }
            const size_t pix = (size_t)b * N_TOK + (size_t)y * W_IMG + x;
            const float4 av = *(const float4*)(add_ + pix * C_ + c0);
            *(float4*)(out + pix * C_ + c0) = make_float4(
                ax * sc.x + sh.x + av.x, ay * sc.y + sh.y + av.y,
                az * sc.z + sh.z + av.z, aw * sc.w + sh.w + av.w);
        }
    }
}

// ---------------------------------------------------------------------------
// QK^T logits + per-row max (scaled).
// ---------------------------------------------------------------------------
__global__ __launch_bounds__(256) void qk_kernel(
    const float* __restrict__ q, const float* __restrict__ k,
    float* __restrict__ attnL, float* __restrict__ mrow_g)
{
    int bh = blockIdx.x;
    int b = bh >> 3, head = bh & 7;
    __shared__ float qs[64][33];
    __shared__ float ks[64][33];
    int tid = threadIdx.x;
    for (int t = tid; t < 512; t += 256) {
        int i = t >> 3, dq = (t & 7) * 4;
        const float4 qv = *(const float4*)(q + ((size_t)(b * 64 + i) * C_ + head * 32 + dq));
        const float4 kv = *(const float4*)(k + ((size_t)(b * 64 + i) * C_ + head * 32 + dq));
        qs[i][dq + 0] = qv.x; qs[i][dq + 1] = qv.y; qs[i][dq + 2] = qv.z; qs[i][dq + 3] = qv.w;
        ks[i][dq + 0] = kv.x; ks[i][dq + 1] = kv.y; ks[i][dq + 2] = kv.z; ks[i][dq + 3] = kv.w;
    }
    __syncthreads();
    int i  = tid >> 2;
    int jb = (tid & 3) * 16;
    float qr[32];
#pragma unroll
    for (int d = 0; d < 32; ++d) qr[d] = qs[i][d];
    float* outp = attnL + (size_t)bh * 4096 + i * 64 + jb;
    float mloc = -1e30f;
#pragma unroll
    for (int j = 0; j < 16; ++j) {
        float s = 0.f;
#pragma unroll
        for (int d = 0; d < 32; ++d) s = fmaf(qr[d], ks[jb + j][d], s);
        float sv = s * 0.0625f;          // C^-0.5
        outp[j] = sv;
        mloc = fmaxf(mloc, sv);
    }
    mloc = fmaxf(mloc, __shfl_xor(mloc, 1));
    mloc = fmaxf(mloc, __shfl_xor(mloc, 2));
    if ((tid & 3) == 0) mrow_g[bh * 64 + i] = mloc;
}

// ---------------------------------------------------------------------------
// Fused upsample(logits)->softmax-weights->PV via MFMA (verified R6+).
// ---------------------------------------------------------------------------
#define S_ALS 0
#define S_P   1792
#define S_VH  4096
#define S_VL  5248
#define S_RY  6400
#define S_ZP  7168
__global__ __launch_bounds__(256, 5) void attn_pv_kernel(
    const float* __restrict__ attnL,
    const float* __restrict__ mrow_g,
    const float* __restrict__ v,
    float* __restrict__ part_o,
    float* __restrict__ part_z)
{
    __shared__ unsigned sm[7424];
    float* smf = (float*)sm;

    const int blk   = blockIdx.x;
    const int xcd   = blk & 7;
    const int r8    = blk >> 3;
    const int b     = xcd + 8 * (r8 >> 6);
    const int rem   = r8 & 63;
    const int head  = rem >> 3;
    const int chunk = rem & 7;
    const int bh    = b * 8 + head;
    const int jb    = min(max(chunk - 1, 0), 5);

    const int tid  = threadIdx.x;
    const int lane = tid & 63;
    const int w    = tid >> 6;
    const int l15  = lane & 15, kb = lane >> 4;
    const int i    = tid >> 2;
    const int dg   = tid & 3;

    for (int u = tid; u < 384; u += 256) {
        int row = u / 6, cc = u % 6;
        float4 va = *(const float4*)(attnL + (size_t)bh * 4096 + row * 64 + jb * 8 + cc * 4);
        *(float4*)&smf[S_ALS + row * 28 + cc * 4] = va;
    }
    sm[S_P + (tid >> 2) * 36 + 28 + (tid & 3)] = 0;
    {
        int base = (tid < 128) ? S_VH : S_VL;
        int q2 = tid & 127;
        sm[base + (q2 >> 2) * 36 + 28 + (q2 & 3)] = 0;
    }
    const float mr = mrow_g[bh * 64 + i];

    int   x0a[14]; float txa[14];
#pragma unroll
    for (int j = 0; j < 14; ++j) {
        int i0, i1; float t;
        up_coef(dg * 14 + j, i0, i1, t);
        x0a[j] = i0; txa[j] = t;
    }

    f32x4 acc[2];
    acc[0] = (f32x4)(0.0f); acc[1] = (f32x4)(0.0f);
    float zacc = 0.0f;

    for (int rr = 0; rr < 7; ++rr) {
        const int y = chunk * 7 + rr;
        __syncthreads();

        float4 va, vb;
        if (tid < 224) {
            int x2 = tid >> 3, d0 = (tid & 7) * 4;
            const float* vp = v + ((size_t)b * N_TOK + y * W_IMG + 2 * x2) * C_ + head * 32 + d0;
            va = *(const float4*)vp;
            vb = *(const float4*)(vp + C_);
        }
        {
            int y0, y1; float ty;
            up_coef(y, y0, y1, ty);
#pragma unroll
            for (int kk2 = dg; kk2 < 9; kk2 += 4) {
                int ks2 = kk2 < 8 ? kk2 : 7;
                float a0 = smf[S_ALS + i * 28 + (y0 - jb) * 8 + ks2];
                float a1 = smf[S_ALS + i * 28 + (y1 - jb) * 8 + ks2];
                smf[S_RY + i * 12 + kk2] = fmaf(ty, a1 - a0, a0) - mr;
            }
        }
        if (tid < 224) {
            int x2 = tid >> 3, d0 = (tid & 7) * 4;
            float ae[4] = {va.x, va.y, va.z, va.w};
            float be[4] = {vb.x, vb.y, vb.z, vb.w};
#pragma unroll
            for (int j = 0; j < 4; ++j) {
                unsigned ua = __float_as_uint(ae[j]), ha = ua & 0xFFFF0000u;
                unsigned ub = __float_as_uint(be[j]), hb2 = ub & 0xFFFF0000u;
                sm[S_VH + (d0 + j) * 36 + x2] = (ha >> 16) | hb2;
                float la = ae[j] - __uint_as_float(ha);
                float lb = be[j] - __uint_as_float(hb2);
                sm[S_VL + (d0 + j) * 36 + x2] =
                    (__float_as_uint(la) >> 16) | (__float_as_uint(lb) & 0xFFFF0000u);
            }
        }
        __syncthreads();

#pragma unroll
        for (int j = 0; j < 7; ++j) {
            float r0 = smf[S_RY + i * 12 + x0a[2 * j]];
            float r1 = smf[S_RY + i * 12 + x0a[2 * j] + 1];
            float l0 = fmaf(txa[2 * j], r1 - r0, r0);
            float r2 = smf[S_RY + i * 12 + x0a[2 * j + 1]];
            float r3 = smf[S_RY + i * 12 + x0a[2 * j + 1] + 1];
            float l1 = fmaf(txa[2 * j + 1], r3 - r2, r2);
            float p0 = __expf(l0), p1 = __expf(l1);
            zacc += p0 + p1;
            sm[S_P + i * 36 + dg * 7 + j] = pack2_bf16(p0, p1);
        }
        __syncthreads();

#pragma unroll
        for (int s = 0; s < 2; ++s) {
            bf16x8 pa = *(const bf16x8*)&sm[S_P + (w * 16 + l15) * 36 + s * 16 + kb * 4];
#pragma unroll
            for (int n = 0; n < 2; ++n) {
                bf16x8 bhv = *(const bf16x8*)&sm[S_VH + (n * 16 + l15) * 36 + s * 16 + kb * 4];
                bf16x8 blv = *(const bf16x8*)&sm[S_VL + (n * 16 + l15) * 36 + s * 16 + kb * 4];
                acc[n] = __builtin_amdgcn_mfma_f32_16x16x32_bf16(pa, bhv, acc[n], 0, 0, 0);
                acc[n] = __builtin_amdgcn_mfma_f32_16x16x32_bf16(pa, blv, acc[n], 0, 0, 0);
            }
        }
    }

    smf[S_ZP + i * 4 + dg] = zacc;
    __syncthreads();
    if (tid < 64) {
        float zt = smf[S_ZP + tid * 4] + smf[S_ZP + tid * 4 + 1] +
                   smf[S_ZP + tid * 4 + 2] + smf[S_ZP + tid * 4 + 3];
        part_z[((size_t)bh * NCH + chunk) * 64 + tid] = zt;
    }
    const int row4 = (lane >> 4) * 4;
#pragma unroll
    for (int n = 0; n < 2; ++n)
#pragma unroll
        for (int r2 = 0; r2 < 4; ++r2) {
            int i2 = w * 16 + row4 + r2;
            int d  = n * 16 + l15;
            part_o[(((size_t)bh * NCH + chunk) * 64 + i2) * 32 + d] = acc[n][r2];
        }
}

// ---------------------------------------------------------------------------
// Combine partials -> o_small [B][64][C], divide by Z.
// ---------------------------------------------------------------------------
__global__ __launch_bounds__(256) void combine_kernel(
    const float* __restrict__ part_o, const float* __restrict__ part_z,
    float* __restrict__ o_small)
{
    int idx = blockIdx.x * 256 + threadIdx.x;
    if (idx >= B_ * 64 * C_) return;
    int c = idx % C_;
    int g = (idx / C_) % 64;
    int b = idx / (C_ * 64);
    int head = c >> 5, d = c & 31;
    int bh = b * 8 + head;
    float oo = 0.f, zz = 0.f;
    for (int ch = 0; ch < NCH; ++ch) {
        oo += part_o[(((size_t)bh * NCH + ch) * 64 + g) * 32 + d];
        zz += part_z[((size_t)bh * NCH + ch) * 64 + g];
    }
    o_small[idx] = oo / zz;
}

// ---------------------------------------------------------------------------
extern "C" void kernel_launch(void* const* d_in, const int* in_sizes, int n_in,
                              void* d_out, int out_size, void* d_ws, size_t ws_size,
                              hipStream_t stream)
{
    const float* x    = (const float*)d_in[0];
    const float* Wv   = (const float*)d_in[1];
    const float* c1w  = (const float*)d_in[2];
    const float* b1g  = (const float*)d_in[3];
    const float* b1b  = (const float*)d_in[4];
    const float* b1m  = (const float*)d_in[5];
    const float* b1v  = (const float*)d_in[6];
    const float* c2w  = (const float*)d_in[7];
    const float* b2g  = (const float*)d_in[8];
    const float* b2b  = (const float*)d_in[9];
    const float* b2m  = (const float*)d_in[10];
    const float* b2v  = (const float*)d_in[11];
    const float* vupw = (const float*)d_in[12];
    const float* b3g  = (const float*)d_in[13];
    const float* b3b  = (const float*)d_in[14];
    const float* b3m  = (const float*)d_in[15];
    const float* b3v  = (const float*)d_in[16];
    const float* Wp   = (const float*)d_in[17];
    const float* bp   = (const float*)d_in[18];
    float* out = (float*)d_out;
    float* ws  = (float*)d_ws;

    const size_t SZ = (size_t)B_ * N_TOK * C_;
    float* v       = ws;
    float* s1g     = v   + SZ;      // unused (layout stability)
    float* s2g     = s1g + SZ;
    float* q       = s2g + SZ;
    float* kk      = q  + (size_t)B_ * 64 * C_;
    float* attnL   = kk + (size_t)B_ * 64 * C_;
    float* part_o  = attnL  + (size_t)B_ * 8 * 64 * 64;
    float* part_z  = part_o + (size_t)B_ * 8 * NCH * 64 * 32;
    float* o_small = part_z + (size_t)B_ * 8 * NCH * 64;
    float* wT1     = o_small + (size_t)B_ * 64 * C_;
    float* wT2     = wT1 + 9 * C_;
    float* wT3     = wT2 + 9 * C_;
    float* sc1     = wT3 + 9 * C_;
    float* sh1     = sc1 + C_;
    float* sc2     = sh1 + C_;
    float* sh2     = sc2 + C_;
    float* sc3     = sh2 + C_;
    float* sh3     = sc3 + C_;
    float* mrow_g  = sh3 + C_;

    const int M = B_ * N_TOK;

    prep_kernel<<<10, 256, 0, stream>>>(c1w, c2w, vupw,
        b1g, b1b, b1m, b1v, b2g, b2b, b2m, b2v, b3g, b3b, b3m, b3v,
        wT1, wT2, wT3, sc1, sh1, sc2, sh2, sc3, sh3);
    gemm_nt_mfma_kernel<<<(M / 128) * (C_ / 128), 256, 0, stream>>>(x, Wv, nullptr, v, M, C_);
    dwconv12_fused_kernel<<<4096, 256, 0, stream>>>(v, wT1, sc1, sh1, wT2, sc2, sh2, s2g, q, kk);
    qk_kernel<<<B_ * 8, 256, 0, stream>>>(q, kk, attnL, mrow_g);
    attn_pv_kernel<<<B_ * 8 * NCH, 256, 0, stream>>>(attnL, mrow_g, v, part_o, part_z);
    combine_kernel<<<B_ * 64 * C_ / 256, 256, 0, stream>>>(part_o, part_z, o_small);
    dwconv_up_bn_add_kernel<<<1024, 256, 0, stream>>>(o_small, wT3, sc3, sh3, s2g, v);
    gemm_nt_mfma_kernel<<<(M / 128) * (C_ / 128), 256, 0, stream>>>(v, Wp, bp, out, M, C_);
}

// Round 26
// 179.782 us; speedup vs baseline: 1.0725x; 1.0725x over previous
//
#include <hip/hip_runtime.h>
#include <math.h>

// Problem constants (LocallyEnhancedAttention: B=16, N=3136, C=256, SR=7, HEADS=8)
#define B_     16
#define H_IMG  56
#define W_IMG  56
#define N_TOK  3136      // 56*56
#define C_     256
#define C4_    64        // C_/4
#define NHEAD  8
#define HDIM   32
#define NCH    8         // attn chunks (each = 7 image rows)

typedef float f32x4 __attribute__((ext_vector_type(4)));
typedef __bf16 bf16x8 __attribute__((ext_vector_type(8)));

// gelu(x) = 0.5 x (1 + erf(x/sqrt(2))) with branchless poly erf
// (Abramowitz-Stegun 7.1.26, |err| <= 1.5e-7).
__device__ __forceinline__ float geluf(float x) {
    float a = fabsf(x) * 0.70710678118654752f;
    float t = 1.0f / fmaf(0.3275911f, a, 1.0f);
    float poly = t * fmaf(t, fmaf(t, fmaf(t, fmaf(t, 1.061405429f, -1.453152027f),
                        1.421413741f), -0.284496736f), 0.254829592f);
    float erfa = fmaf(-poly, __expf(-a * a), 1.0f);
    float erfs = copysignf(erfa, x);
    return 0.5f * x * (1.0f + erfs);
}

// 8 -> 56 bilinear (half-pixel + edge renormalize == index clamp). f = (o-3)/7
__device__ __forceinline__ void up_coef(int o, int& i0, int& i1, float& t) {
    float f  = (float)(o - 3) * (1.0f / 7.0f);
    float fl = floorf(f);
    int   ii = (int)fl;
    t = f - fl;
    if (ii < 0)       { i0 = 0; i1 = 0; t = 0.0f; }
    else if (ii >= 7) { i0 = 7; i1 = 7; t = 0.0f; }
    else              { i0 = ii; i1 = ii + 1; }
}

__device__ __forceinline__ void split_bf16(float4 f, uint2& hi, uint2& lo) {
    unsigned u0 = __float_as_uint(f.x), u1 = __float_as_uint(f.y);
    unsigned u2 = __float_as_uint(f.z), u3 = __float_as_uint(f.w);
    unsigned h0 = u0 & 0xFFFF0000u, h1 = u1 & 0xFFFF0000u;
    unsigned h2 = u2 & 0xFFFF0000u, h3 = u3 & 0xFFFF0000u;
    hi = make_uint2((h0 >> 16) | h1, (h2 >> 16) | h3);
    float l0 = f.x - __uint_as_float(h0);
    float l1 = f.y - __uint_as_float(h1);
    float l2 = f.z - __uint_as_float(h2);
    float l3 = f.w - __uint_as_float(h3);
    lo = make_uint2((__float_as_uint(l0) >> 16) | (__float_as_uint(l1) & 0xFFFF0000u),
                    (__float_as_uint(l2) >> 16) | (__float_as_uint(l3) & 0xFFFF0000u));
}

__device__ __forceinline__ unsigned pack2_bf16(float a, float b) {
    __bf16 ha = (__bf16)a, hb = (__bf16)b;
    unsigned short ua = __builtin_bit_cast(unsigned short, ha);
    unsigned short ub = __builtin_bit_cast(unsigned short, hb);
    return (unsigned)ua | ((unsigned)ub << 16);
}

// Async global->LDS, 16B per lane (wave-uniform LDS base + lane*16).
__device__ __forceinline__ void gload_lds16(const float* g, float* l) {
    __builtin_amdgcn_global_load_lds(
        (const __attribute__((address_space(1))) unsigned int*)g,
        (__attribute__((address_space(3))) unsigned int*)l, 16, 0, 0);
}

// ---------------------------------------------------------------------------
// Prep (PARALLEL): blocks 0-8 transpose tap t of all 3 weight sets; block 9
// folds BN into scale/shift.
// ---------------------------------------------------------------------------
__global__ void prep_kernel(
    const float* __restrict__ w1, const float* __restrict__ w2, const float* __restrict__ w3,
    const float* __restrict__ g1, const float* __restrict__ b1, const float* __restrict__ m1, const float* __restrict__ v1,
    const float* __restrict__ g2, const float* __restrict__ b2, const float* __restrict__ m2, const float* __restrict__ v2,
    const float* __restrict__ g3, const float* __restrict__ b3, const float* __restrict__ m3, const float* __restrict__ v3,
    float* __restrict__ wT1, float* __restrict__ wT2, float* __restrict__ wT3,
    float* __restrict__ sc1, float* __restrict__ sh1,
    float* __restrict__ sc2, float* __restrict__ sh2,
    float* __restrict__ sc3, float* __restrict__ sh3)
{
    int c = threadIdx.x;
    int blk = blockIdx.x;
    if (blk < 9) {
        wT1[blk * C_ + c] = w1[c * 9 + blk];
        wT2[blk * C_ + c] = w2[c * 9 + blk];
        wT3[blk * C_ + c] = w3[c * 9 + blk];
    } else {
        float s1 = g1[c] * rsqrtf(v1[c] + 1e-5f); sc1[c] = s1; sh1[c] = b1[c] - m1[c] * s1;
        float s2 = g2[c] * rsqrtf(v2[c] + 1e-5f); sc2[c] = s2; sh2[c] = b2[c] - m2[c] * s2;
        float s3 = g3[c] * rsqrtf(v3[c] + 1e-5f); sc3[c] = s3; sh3[c] = b3[c] - m3[c] * s3;
    }
}

// ---------------------------------------------------------------------------
// MFMA GEMM (NT) — m97 staging + T1 swizzle, 3 blocks/CU (verified).
// ---------------------------------------------------------------------------
__global__ __launch_bounds__(256, 3) void gemm_nt_mfma_kernel(
    const float* __restrict__ A, const float* __restrict__ Bm,
    const float* __restrict__ bias, float* __restrict__ C, int M, int N)
{
    __shared__ float lds[8192];
    const int tid  = threadIdx.x;
    const int nb   = N >> 7;
    const int nwg  = (M >> 7) * nb;
    const int cpx  = nwg >> 3;
    const int bid  = blockIdx.x;
    const int swz  = (bid & 7) * cpx + (bid >> 3);
    const int bx   = swz % nb;
    const int by   = swz / nb;
    const int lane = tid & 63;
    const int wv   = tid >> 6;
    const int wr   = wv >> 1, wc = wv & 1;
    const int l15  = lane & 15, kb = lane >> 4;

    const float* Abase = A  + (size_t)(by * 128) * 256;
    const float* Bbase = Bm + (size_t)(bx * 128) * 256;

    f32x4 acc[4][4];
#pragma unroll
    for (int m = 0; m < 4; ++m)
#pragma unroll
        for (int n = 0; n < 4; ++n) acc[m][n] = (f32x4)(0.0f);

    int srow[4], ssk[4];
#pragma unroll
    for (int i = 0; i < 4; ++i) {
        int u = i * 256 + tid;
        srow[i] = u >> 3;
        ssk[i]  = ((u & 7) ^ (srow[i] & 7)) << 2;
    }

#pragma unroll
    for (int k0 = 0; k0 < 256; k0 += 32) {
        __syncthreads();
#pragma unroll
        for (int i = 0; i < 4; ++i) {
            int u = i * 256 + tid;
            gload_lds16(Abase + (size_t)srow[i] * 256 + k0 + ssk[i], &lds[u * 4]);
        }
#pragma unroll
        for (int i = 0; i < 4; ++i) {
            int u = i * 256 + tid;
            gload_lds16(Bbase + (size_t)srow[i] * 256 + k0 + ssk[i], &lds[4096 + u * 4]);
        }
        __syncthreads();

        bf16x8 ah[4], al[4], bh[4], bl[4];
#pragma unroll
        for (int m = 0; m < 4; ++m) {
            int r = wr * 64 + m * 16 + l15;
            float4 f0 = *(const float4*)&lds[r * 32 + ((((kb * 2)    ) ^ (r & 7)) << 2)];
            float4 f1 = *(const float4*)&lds[r * 32 + ((((kb * 2) + 1) ^ (r & 7)) << 2)];
            uint2 h0, l0, h1, l1;
            split_bf16(f0, h0, l0);
            split_bf16(f1, h1, l1);
            ah[m] = __builtin_bit_cast(bf16x8, make_uint4(h0.x, h0.y, h1.x, h1.y));
            al[m] = __builtin_bit_cast(bf16x8, make_uint4(l0.x, l0.y, l1.x, l1.y));
        }
#pragma unroll
        for (int n = 0; n < 4; ++n) {
            int r = wc * 64 + n * 16 + l15;
            float4 f0 = *(const float4*)&lds[4096 + r * 32 + ((((kb * 2)    ) ^ (r & 7)) << 2)];
            float4 f1 = *(const float4*)&lds[4096 + r * 32 + ((((kb * 2) + 1) ^ (r & 7)) << 2)];
            uint2 h0, l0, h1, l1;
            split_bf16(f0, h0, l0);
            split_bf16(f1, h1, l1);
            bh[n] = __builtin_bit_cast(bf16x8, make_uint4(h0.x, h0.y, h1.x, h1.y));
            bl[n] = __builtin_bit_cast(bf16x8, make_uint4(l0.x, l0.y, l1.x, l1.y));
        }
#pragma unroll
        for (int m = 0; m < 4; ++m)
#pragma unroll
            for (int n = 0; n < 4; ++n) {
                acc[m][n] = __builtin_amdgcn_mfma_f32_16x16x32_bf16(ah[m], bh[n], acc[m][n], 0, 0, 0);
                acc[m][n] = __builtin_amdgcn_mfma_f32_16x16x32_bf16(ah[m], bl[n], acc[m][n], 0, 0, 0);
                acc[m][n] = __builtin_amdgcn_mfma_f32_16x16x32_bf16(al[m], bh[n], acc[m][n], 0, 0, 0);
            }
    }

    const int rb = by * 128 + wr * 64 + kb * 4;
    const int cb = bx * 128 + wc * 64 + l15;
#pragma unroll
    for (int n = 0; n < 4; ++n) {
        int col = cb + n * 16;
        float bv = bias ? bias[col] : 0.0f;
#pragma unroll
        for (int m = 0; m < 4; ++m) {
            int row = rb + m * 16;
#pragma unroll
            for (int r = 0; r < 4; ++r)
                C[(size_t)(row + r) * N + col] = acc[m][n][r] + bv;
        }
    }
}

// ---------------------------------------------------------------------------
// FUSED conv1+conv2, quarter-channel split, LDS-staged input tile
// (R24-verified: 59 us — 17-stride pad, separate ps, (256,4), VGPR 56).
// ---------------------------------------------------------------------------
__global__ __launch_bounds__(256, 4) void dwconv12_fused_kernel(
    const float* __restrict__ v,
    const float* __restrict__ wT1, const float* __restrict__ sc1v, const float* __restrict__ sh1v,
    const float* __restrict__ wT2, const float* __restrict__ sc2v, const float* __restrict__ sh2v,
    float* __restrict__ s2g, float* __restrict__ qpool, float* __restrict__ kpool)
{
    __shared__ float4 sg[121 * 17];   // input tile, then gelu(s1) (first 81 rows)
    __shared__ float4 ps[16][16];     // pool partials

    const int blk = blockIdx.x;
    const int xcd = blk & 7;
    const int j   = blk >> 3;              // 0..511
    const int b   = xcd + 8 * (j >> 8);    // 2 images per XCD
    const int rem = j & 255;
    const int g   = rem >> 2;
    const int ch  = rem & 3;
    const int gy  = g >> 3, gx = g & 7;
    const int tid = threadIdx.x;
    const int q16 = tid & 15;
    const int slot = tid >> 4;             // 0..15
    const int c0  = ch * 64 + q16 * 4;

    const float4 sc1 = *(const float4*)(sc1v + c0);
    const float4 sh1 = *(const float4*)(sh1v + c0);

    float4 w1r[9];
#pragma unroll
    for (int t = 0; t < 9; ++t) w1r[t] = *(const float4*)(wT1 + t * C_ + c0);

    const int y0 = gy * 7, x0 = gx * 7;
    const float* inb = v + (size_t)b * N_TOK * C_ + ch * 64;

    // ---- A1: cooperative 11x11 input tile load (zeros outside image) ----
    for (int idx = tid; idx < 121 * 16; idx += 256) {
        int pin = idx >> 4, q = idx & 15;
        int ry  = pin / 11;
        int iy  = y0 - 2 + ry;
        int ix  = x0 - 2 + (pin - ry * 11);
        float4 val = make_float4(0.f, 0.f, 0.f, 0.f);
        if ((unsigned)iy < (unsigned)H_IMG && (unsigned)ix < (unsigned)W_IMG)
            val = *(const float4*)(inb + (size_t)(iy * W_IMG + ix) * C_ + q * 4);
        sg[pin * 17 + q] = val;
    }
    __syncthreads();

    // ---- A2: conv1 + BN from LDS into registers (static indexing) ----
    float4 s1r[6];
    float4 qacc = make_float4(0.f, 0.f, 0.f, 0.f);
#pragma unroll
    for (int it = 0; it < 6; ++it) {
        const int p = slot + it * 16;
        if (p < 81) {
            const int py = p / 9, px = p - (p / 9) * 9;
            float cx = 0.f, cy = 0.f, cz = 0.f, cw = 0.f;
#pragma unroll
            for (int dy = 0; dy < 3; ++dy)
#pragma unroll
                for (int dx = 0; dx < 3; ++dx) {
                    const float4 iv = sg[((py + dy) * 11 + (px + dx)) * 17 + q16];
                    const float4 w  = w1r[dy * 3 + dx];
                    cx = fmaf(iv.x, w.x, cx);
                    cy = fmaf(iv.y, w.y, cy);
                    cz = fmaf(iv.z, w.z, cz);
                    cw = fmaf(iv.w, w.w, cw);
                }
            float4 s1;
            s1.x = cx * sc1.x + sh1.x;
            s1.y = cy * sc1.y + sh1.y;
            s1.z = cz * sc1.z + sh1.z;
            s1.w = cw * sc1.w + sh1.w;
            s1r[it] = s1;
            const float msk = (py >= 1 && py <= 7 && px >= 1 && px <= 7) ? 1.0f : 0.0f;
            qacc.x = fmaf(msk, s1.x, qacc.x);
            qacc.y = fmaf(msk, s1.y, qacc.y);
            qacc.z = fmaf(msk, s1.z, qacc.z);
            qacc.w = fmaf(msk, s1.w, qacc.w);
        } else {
            s1r[it] = make_float4(0.f, 0.f, 0.f, 0.f);
        }
    }
    __syncthreads();   // all tile reads done before overwrite

    // ---- A3: write gelu(s1) into sg (0 for out-of-image outputs) ----
#pragma unroll
    for (int it = 0; it < 6; ++it) {
        const int p = slot + it * 16;
        if (p < 81) {
            const int py = p / 9, px = p - (p / 9) * 9;
            const int oy = y0 - 1 + py, ox = x0 - 1 + px;
            const bool pv = ((unsigned)oy < (unsigned)H_IMG) && ((unsigned)ox < (unsigned)W_IMG);
            const float4 s1 = s1r[it];
            float4 o;
            o.x = pv ? geluf(s1.x) : 0.0f;
            o.y = pv ? geluf(s1.y) : 0.0f;
            o.z = pv ? geluf(s1.z) : 0.0f;
            o.w = pv ? geluf(s1.w) : 0.0f;
            sg[p * 17 + q16] = o;
        }
    }
    ps[slot][q16] = qacc;
    __syncthreads();

    // ---- q-pool reduce + write ----
    if (tid < 16) {
        float4 s = ps[0][tid];
#pragma unroll
        for (int t = 1; t < 16; ++t) {
            float4 u = ps[t][tid];
            s.x += u.x; s.y += u.y; s.z += u.z; s.w += u.w;
        }
        const float r = 1.0f / 49.0f;
        *(float4*)(qpool + ((size_t)b * 64 + g) * C_ + ch * 64 + tid * 4) =
            make_float4(s.x * r, s.y * r, s.z * r, s.w * r);
    }

    // ---- Phase C: conv2 from LDS ----
    float4 w2r[9];
#pragma unroll
    for (int t = 0; t < 9; ++t) w2r[t] = *(const float4*)(wT2 + t * C_ + c0);
    const float4 sc2 = *(const float4*)(sc2v + c0);
    const float4 sh2 = *(const float4*)(sh2v + c0);

    float4 kacc = make_float4(0.f, 0.f, 0.f, 0.f);
    for (int p2 = slot; p2 < 49; p2 += 16) {
        int qy = p2 / 7, qx = p2 - qy * 7;
        float cx = 0.f, cy = 0.f, cz = 0.f, cw = 0.f;
#pragma unroll
        for (int dy = 0; dy < 3; ++dy)
#pragma unroll
            for (int dx = 0; dx < 3; ++dx) {
                const float4 t4 = sg[((qy + dy) * 9 + (qx + dx)) * 17 + q16];
                const float4 w  = w2r[dy * 3 + dx];
                cx = fmaf(t4.x, w.x, cx);
                cy = fmaf(t4.y, w.y, cy);
                cz = fmaf(t4.z, w.z, cz);
                cw = fmaf(t4.w, w.w, cw);
            }
        float s2x = cx * sc2.x + sh2.x;
        float s2y = cy * sc2.y + sh2.y;
        float s2z = cz * sc2.z + sh2.z;
        float s2w = cw * sc2.w + sh2.w;
        kacc.x += s2x; kacc.y += s2y; kacc.z += s2z; kacc.w += s2w;
        *(float4*)(s2g + ((size_t)b * N_TOK + (y0 + qy) * W_IMG + (x0 + qx)) * C_ + c0) =
            make_float4(geluf(s2x), geluf(s2y), geluf(s2z), geluf(s2w));
    }
    __syncthreads();   // ps reuse
    ps[slot][q16] = kacc;
    __syncthreads();
    if (tid < 16) {
        float4 s = ps[0][tid];
#pragma unroll
        for (int t = 1; t < 16; ++t) {
            float4 u = ps[t][tid];
            s.x += u.x; s.y += u.y; s.z += u.z; s.w += u.w;
        }
        const float r = 1.0f / 49.0f;
        *(float4*)(kpool + ((size_t)b * 64 + g) * C_ + ch * 64 + tid * 4) =
            make_float4(s.x * r, s.y * r, s.z * r, s.w * r);
    }
}

// ---------------------------------------------------------------------------
// FUSED conv3x3(bilinear_up(o_small)) + BN + add — hoisted (verified R13+).
// ---------------------------------------------------------------------------
__global__ __launch_bounds__(256, 3) void dwconv_up_bn_add_kernel(
    const float* __restrict__ osm, const float* __restrict__ wT,
    const float* __restrict__ scv, const float* __restrict__ shv,
    const float* __restrict__ add_, float* __restrict__ out)
{
    const int blk = blockIdx.x;
    const int xcd = blk & 7;
    const int j   = blk >> 3;
    const int b   = xcd + 8 * (j >> 6);
    const int g   = j & 63;
    const int gy  = g >> 3, gx = g & 7;
    const int tid = threadIdx.x;
    const int c4  = tid & 63;
    const int wv  = tid >> 6;
    const int c0  = c4 * 4;

    float4 wr[9];
#pragma unroll
    for (int t = 0; t < 9; ++t) wr[t] = *(const float4*)(wT + t * C_ + c0);
    const float4 sc = *(const float4*)(scv + c0);
    const float4 sh = *(const float4*)(shv + c0);

    const float* ob = osm + (size_t)b * 64 * C_ + c0;
    const int cry0 = max(gy - 1, 0), cry2 = min(gy + 1, 7);
    const int crx0 = max(gx - 1, 0), crx2 = min(gx + 1, 7);
    float4 P[3][3];
#pragma unroll
    for (int ri = 0; ri < 3; ++ri) {
        const int rowc = (ri == 0) ? cry0 : ((ri == 1) ? gy : cry2);
        P[ri][0] = *(const float4*)(ob + (size_t)(rowc * 8 + crx0) * C_);
        P[ri][1] = *(const float4*)(ob + (size_t)(rowc * 8 + gx)   * C_);
        P[ri][2] = *(const float4*)(ob + (size_t)(rowc * 8 + crx2) * C_);
    }

    for (int cpass = 0; cpass < 2; ++cpass) {
        const int xi = wv + cpass * 4;
        if (xi >= 7) break;
        const int x = gx * 7 + xi;

        float axw[3][3];
#pragma unroll
        for (int e = 0; e < 3; ++e) {
            int xx = x - 1 + e;
            if (xx >= 0 && xx < W_IMG) {
                int i0, i1; float t;
                up_coef(xx, i0, i1, t);
                const bool r0 = (i0 - gx + 1) == 0;
                axw[e][0] = r0 ? (1.0f - t) : 0.0f;
                axw[e][1] = r0 ? t : (1.0f - t);
                axw[e][2] = r0 ? 0.0f : t;
            } else {
                axw[e][0] = 0.0f; axw[e][1] = 0.0f; axw[e][2] = 0.0f;
            }
        }

        float4 S[3][3];
#pragma unroll
        for (int d = 0; d < 3; ++d) {
            float4 cw0, cw1, cw2;
#pragma unroll
            for (int ci = 0; ci < 3; ++ci) {
                float4 c;
                c.x = wr[d*3+0].x * axw[0][ci] + wr[d*3+1].x * axw[1][ci] + wr[d*3+2].x * axw[2][ci];
                c.y = wr[d*3+0].y * axw[0][ci] + wr[d*3+1].y * axw[1][ci] + wr[d*3+2].y * axw[2][ci];
                c.z = wr[d*3+0].z * axw[0][ci] + wr[d*3+1].z * axw[1][ci] + wr[d*3+2].z * axw[2][ci];
                c.w = wr[d*3+0].w * axw[0][ci] + wr[d*3+1].w * axw[1][ci] + wr[d*3+2].w * axw[2][ci];
                if (ci == 0) cw0 = c; else if (ci == 1) cw1 = c; else cw2 = c;
            }
#pragma unroll
            for (int ri = 0; ri < 3; ++ri) {
                float4 s;
                s.x = cw0.x * P[ri][0].x + cw1.x * P[ri][1].x + cw2.x * P[ri][2].x;
                s.y = cw0.y * P[ri][0].y + cw1.y * P[ri][1].y + cw2.y * P[ri][2].y;
                s.z = cw0.z * P[ri][0].z + cw1.z * P[ri][1].z + cw2.z * P[ri][2].z;
                s.w = cw0.w * P[ri][0].w + cw1.w * P[ri][1].w + cw2.w * P[ri][2].w;
                S[d][ri] = s;
            }
        }

#pragma unroll
        for (int y7 = 0; y7 < 7; ++y7) {
            const int y = gy * 7 + y7;
            float ax = 0.f, ay = 0.f, az = 0.f, aw = 0.f;
#pragma unroll
            for (int d = 0; d < 3; ++d) {
                const int yy = y + d - 1;
                if (yy < 0 || yy >= H_IMG) continue;
                int i0, i1; float ty;
                up_coef(yy, i0, i1, ty);
                const bool hi2 = (i0 - gy + 1) != 0;
                const float4 lo = hi2 ? S[d][1] : S[d][0];
                const float4 hi = hi2 ? S[d][2] : S[d][1];
                ax += fmaf(ty, hi.x - lo.x, lo.x);
                ay += fmaf(ty, hi.y - lo.y, lo.y);
                az += fmaf(ty, hi.z - lo.z, lo.z);
                aw += fmaf(ty, hi.w - lo.w, lo.w);
            }
            const size_t pix = (size_t)b * N_TOK + (size_t)y * W_IMG + x;
            const float4 av = *(const float4*)(add_ + pix * C_ + c0);
            *(float4*)(out + pix * C_ + c0) = make_float4(
                ax * sc.x + sh.x + av.x, ay * sc.y + sh.y + av.y,
                az * sc.z + sh.z + av.z, aw * sc.w + sh.w + av.w);
        }
    }
}

// ---------------------------------------------------------------------------
// QK^T logits + per-row max (scaled).
// ---------------------------------------------------------------------------
__global__ __launch_bounds__(256) void qk_kernel(
    const float* __restrict__ q, const float* __restrict__ k,
    float* __restrict__ attnL, float* __restrict__ mrow_g)
{
    int bh = blockIdx.x;
    int b = bh >> 3, head = bh & 7;
    __shared__ float qs[64][33];
    __shared__ float ks[64][33];
    int tid = threadIdx.x;
    for (int t = tid; t < 512; t += 256) {
        int i = t >> 3, dq = (t & 7) * 4;
        const float4 qv = *(const float4*)(q + ((size_t)(b * 64 + i) * C_ + head * 32 + dq));
        const float4 kv = *(const float4*)(k + ((size_t)(b * 64 + i) * C_ + head * 32 + dq));
        qs[i][dq + 0] = qv.x; qs[i][dq + 1] = qv.y; qs[i][dq + 2] = qv.z; qs[i][dq + 3] = qv.w;
        ks[i][dq + 0] = kv.x; ks[i][dq + 1] = kv.y; ks[i][dq + 2] = kv.z; ks[i][dq + 3] = kv.w;
    }
    __syncthreads();
    int i  = tid >> 2;
    int jb = (tid & 3) * 16;
    float qr[32];
#pragma unroll
    for (int d = 0; d < 32; ++d) qr[d] = qs[i][d];
    float* outp = attnL + (size_t)bh * 4096 + i * 64 + jb;
    float mloc = -1e30f;
#pragma unroll
    for (int j = 0; j < 16; ++j) {
        float s = 0.f;
#pragma unroll
        for (int d = 0; d < 32; ++d) s = fmaf(qr[d], ks[jb + j][d], s);
        float sv = s * 0.0625f;          // C^-0.5
        outp[j] = sv;
        mloc = fmaxf(mloc, sv);
    }
    mloc = fmaxf(mloc, __shfl_xor(mloc, 1));
    mloc = fmaxf(mloc, __shfl_xor(mloc, 2));
    if ((tid & 3) == 0) mrow_g[bh * 64 + i] = mloc;
}

// ---------------------------------------------------------------------------
// Fused upsample(logits)->softmax-weights->PV via MFMA (verified R6+).
// ---------------------------------------------------------------------------
#define S_ALS 0
#define S_P   1792
#define S_VH  4096
#define S_VL  5248
#define S_RY  6400
#define S_ZP  7168
__global__ __launch_bounds__(256, 5) void attn_pv_kernel(
    const float* __restrict__ attnL,
    const float* __restrict__ mrow_g,
    const float* __restrict__ v,
    float* __restrict__ part_o,
    float* __restrict__ part_z)
{
    __shared__ unsigned sm[7424];
    float* smf = (float*)sm;

    const int blk   = blockIdx.x;
    const int xcd   = blk & 7;
    const int r8    = blk >> 3;
    const int b     = xcd + 8 * (r8 >> 6);
    const int rem   = r8 & 63;
    const int head  = rem >> 3;
    const int chunk = rem & 7;
    const int bh    = b * 8 + head;
    const int jb    = min(max(chunk - 1, 0), 5);

    const int tid  = threadIdx.x;
    const int lane = tid & 63;
    const int w    = tid >> 6;
    const int l15  = lane & 15, kb = lane >> 4;
    const int i    = tid >> 2;
    const int dg   = tid & 3;

    for (int u = tid; u < 384; u += 256) {
        int row = u / 6, cc = u % 6;
        float4 va = *(const float4*)(attnL + (size_t)bh * 4096 + row * 64 + jb * 8 + cc * 4);
        *(float4*)&smf[S_ALS + row * 28 + cc * 4] = va;
    }
    sm[S_P + (tid >> 2) * 36 + 28 + (tid & 3)] = 0;
    {
        int base = (tid < 128) ? S_VH : S_VL;
        int q2 = tid & 127;
        sm[base + (q2 >> 2) * 36 + 28 + (q2 & 3)] = 0;
    }
    const float mr = mrow_g[bh * 64 + i];

    int   x0a[14]; float txa[14];
#pragma unroll
    for (int j = 0; j < 14; ++j) {
        int i0, i1; float t;
        up_coef(dg * 14 + j, i0, i1, t);
        x0a[j] = i0; txa[j] = t;
    }

    f32x4 acc[2];
    acc[0] = (f32x4)(0.0f); acc[1] = (f32x4)(0.0f);
    float zacc = 0.0f;

    for (int rr = 0; rr < 7; ++rr) {
        const int y = chunk * 7 + rr;
        __syncthreads();

        float4 va, vb;
        if (tid < 224) {
            int x2 = tid >> 3, d0 = (tid & 7) * 4;
            const float* vp = v + ((size_t)b * N_TOK + y * W_IMG + 2 * x2) * C_ + head * 32 + d0;
            va = *(const float4*)vp;
            vb = *(const float4*)(vp + C_);
        }
        {
            int y0, y1; float ty;
            up_coef(y, y0, y1, ty);
#pragma unroll
            for (int kk2 = dg; kk2 < 9; kk2 += 4) {
                int ks2 = kk2 < 8 ? kk2 : 7;
                float a0 = smf[S_ALS + i * 28 + (y0 - jb) * 8 + ks2];
                float a1 = smf[S_ALS + i * 28 + (y1 - jb) * 8 + ks2];
                smf[S_RY + i * 12 + kk2] = fmaf(ty, a1 - a0, a0) - mr;
            }
        }
        if (tid < 224) {
            int x2 = tid >> 3, d0 = (tid & 7) * 4;
            float ae[4] = {va.x, va.y, va.z, va.w};
            float be[4] = {vb.x, vb.y, vb.z, vb.w};
#pragma unroll
            for (int j = 0; j < 4; ++j) {
                unsigned ua = __float_as_uint(ae[j]), ha = ua & 0xFFFF0000u;
                unsigned ub = __float_as_uint(be[j]), hb2 = ub & 0xFFFF0000u;
                sm[S_VH + (d0 + j) * 36 + x2] = (ha >> 16) | hb2;
                float la = ae[j] - __uint_as_float(ha);
                float lb = be[j] - __uint_as_float(hb2);
                sm[S_VL + (d0 + j) * 36 + x2] =
                    (__float_as_uint(la) >> 16) | (__float_as_uint(lb) & 0xFFFF0000u);
            }
        }
        __syncthreads();

#pragma unroll
        for (int j = 0; j < 7; ++j) {
            float r0 = smf[S_RY + i * 12 + x0a[2 * j]];
            float r1 = smf[S_RY + i * 12 + x0a[2 * j] + 1];
            float l0 = fmaf(txa[2 * j], r1 - r0, r0);
            float r2 = smf[S_RY + i * 12 + x0a[2 * j + 1]];
            float r3 = smf[S_RY + i * 12 + x0a[2 * j + 1] + 1];
            float l1 = fmaf(txa[2 * j + 1], r3 - r2, r2);
            float p0 = __expf(l0), p1 = __expf(l1);
            zacc += p0 + p1;
            sm[S_P + i * 36 + dg * 7 + j] = pack2_bf16(p0, p1);
        }
        __syncthreads();

#pragma unroll
        for (int s = 0; s < 2; ++s) {
            bf16x8 pa = *(const bf16x8*)&sm[S_P + (w * 16 + l15) * 36 + s * 16 + kb * 4];
#pragma unroll
            for (int n = 0; n < 2; ++n) {
                bf16x8 bhv = *(const bf16x8*)&sm[S_VH + (n * 16 + l15) * 36 + s * 16 + kb * 4];
                bf16x8 blv = *(const bf16x8*)&sm[S_VL + (n * 16 + l15) * 36 + s * 16 + kb * 4];
                acc[n] = __builtin_amdgcn_mfma_f32_16x16x32_bf16(pa, bhv, acc[n], 0, 0, 0);
                acc[n] = __builtin_amdgcn_mfma_f32_16x16x32_bf16(pa, blv, acc[n], 0, 0, 0);
            }
        }
    }

    smf[S_ZP + i * 4 + dg] = zacc;
    __syncthreads();
    if (tid < 64) {
        float zt = smf[S_ZP + tid * 4] + smf[S_ZP + tid * 4 + 1] +
                   smf[S_ZP + tid * 4 + 2] + smf[S_ZP + tid * 4 + 3];
        part_z[((size_t)bh * NCH + chunk) * 64 + tid] = zt;
    }
    const int row4 = (lane >> 4) * 4;
#pragma unroll
    for (int n = 0; n < 2; ++n)
#pragma unroll
        for (int r2 = 0; r2 < 4; ++r2) {
            int i2 = w * 16 + row4 + r2;
            int d  = n * 16 + l15;
            part_o[(((size_t)bh * NCH + chunk) * 64 + i2) * 32 + d] = acc[n][r2];
        }
}

// ---------------------------------------------------------------------------
// Combine partials -> o_small [B][64][C], divide by Z.
// ---------------------------------------------------------------------------
__global__ __launch_bounds__(256) void combine_kernel(
    const float* __restrict__ part_o, const float* __restrict__ part_z,
    float* __restrict__ o_small)
{
    int idx = blockIdx.x * 256 + threadIdx.x;
    if (idx >= B_ * 64 * C_) return;
    int c = idx % C_;
    int g = (idx / C_) % 64;
    int b = idx / (C_ * 64);
    int head = c >> 5, d = c & 31;
    int bh = b * 8 + head;
    float oo = 0.f, zz = 0.f;
    for (int ch = 0; ch < NCH; ++ch) {
        oo += part_o[(((size_t)bh * NCH + ch) * 64 + g) * 32 + d];
        zz += part_z[((size_t)bh * NCH + ch) * 64 + g];
    }
    o_small[idx] = oo / zz;
}

// ---------------------------------------------------------------------------
extern "C" void kernel_launch(void* const* d_in, const int* in_sizes, int n_in,
                              void* d_out, int out_size, void* d_ws, size_t ws_size,
                              hipStream_t stream)
{
    const float* x    = (const float*)d_in[0];
    const float* Wv   = (const float*)d_in[1];
    const float* c1w  = (const float*)d_in[2];
    const float* b1g  = (const float*)d_in[3];
    const float* b1b  = (const float*)d_in[4];
    const float* b1m  = (const float*)d_in[5];
    const float* b1v  = (const float*)d_in[6];
    const float* c2w  = (const float*)d_in[7];
    const float* b2g  = (const float*)d_in[8];
    const float* b2b  = (const float*)d_in[9];
    const float* b2m  = (const float*)d_in[10];
    const float* b2v  = (const float*)d_in[11];
    const float* vupw = (const float*)d_in[12];
    const float* b3g  = (const float*)d_in[13];
    const float* b3b  = (const float*)d_in[14];
    const float* b3m  = (const float*)d_in[15];
    const float* b3v  = (const float*)d_in[16];
    const float* Wp   = (const float*)d_in[17];
    const float* bp   = (const float*)d_in[18];
    float* out = (float*)d_out;
    float* ws  = (float*)d_ws;

    const size_t SZ = (size_t)B_ * N_TOK * C_;
    float* v       = ws;
    float* s1g     = v   + SZ;      // unused (layout stability)
    float* s2g     = s1g + SZ;
    float* q       = s2g + SZ;
    float* kk      = q  + (size_t)B_ * 64 * C_;
    float* attnL   = kk + (size_t)B_ * 64 * C_;
    float* part_o  = attnL  + (size_t)B_ * 8 * 64 * 64;
    float* part_z  = part_o + (size_t)B_ * 8 * NCH * 64 * 32;
    float* o_small = part_z + (size_t)B_ * 8 * NCH * 64;
    float* wT1     = o_small + (size_t)B_ * 64 * C_;
    float* wT2     = wT1 + 9 * C_;
    float* wT3     = wT2 + 9 * C_;
    float* sc1     = wT3 + 9 * C_;
    float* sh1     = sc1 + C_;
    float* sc2     = sh1 + C_;
    float* sh2     = sc2 + C_;
    float* sc3     = sh2 + C_;
    float* sh3     = sc3 + C_;
    float* mrow_g  = sh3 + C_;

    const int M = B_ * N_TOK;

    prep_kernel<<<10, 256, 0, stream>>>(c1w, c2w, vupw,
        b1g, b1b, b1m, b1v, b2g, b2b, b2m, b2v, b3g, b3b, b3m, b3v,
        wT1, wT2, wT3, sc1, sh1, sc2, sh2, sc3, sh3);
    gemm_nt_mfma_kernel<<<(M / 128) * (C_ / 128), 256, 0, stream>>>(x, Wv, nullptr, v, M, C_);
    dwconv12_fused_kernel<<<4096, 256, 0, stream>>>(v, wT1, sc1, sh1, wT2, sc2, sh2, s2g, q, kk);
    qk_kernel<<<B_ * 8, 256, 0, stream>>>(q, kk, attnL, mrow_g);
    attn_pv_kernel<<<B_ * 8 * NCH, 256, 0, stream>>>(attnL, mrow_g, v, part_o, part_z);
    combine_kernel<<<B_ * 64 * C_ / 256, 256, 0, stream>>>(part_o, part_z, o_small);
    dwconv_up_bn_add_kernel<<<1024, 256, 0, stream>>>(o_small, wT3, sc3, sh3, s2g, v);
    gemm_nt_mfma_kernel<<<(M / 128) * (C_ / 128), 256, 0, stream>>>(v, Wp, bp, out, M, C_);
}